// Round 3
// baseline (1669.442 us; speedup 1.0000x reference)
//
#include <hip/hip_runtime.h>
#include <stdint.h>

typedef __attribute__((ext_vector_type(8))) short bf16x8;
typedef __attribute__((ext_vector_type(4))) float f32x4;
typedef unsigned short u16;

#define GLD_LDS16(g, l) __builtin_amdgcn_global_load_lds( \
    (const __attribute__((address_space(1))) void*)(g),   \
    (__attribute__((address_space(3))) void*)(l), 16, 0, 0)

#define PB() do { __builtin_amdgcn_sched_barrier(0); \
                  __builtin_amdgcn_s_barrier();      \
                  __builtin_amdgcn_sched_barrier(0); } while (0)

#define ACCUM(d, a_, b_) d = __builtin_amdgcn_mfma_f32_16x16x32_bf16(a_, b_, d, 0, 0, 0)

__device__ __forceinline__ u16 f2bf(float f) {
  union { float f; uint32_t u; } a; a.f = f;
  uint32_t u = a.u;
  return (u16)((u + 0x7fffu + ((u >> 16) & 1u)) >> 16);
}
__device__ __forceinline__ float bf2f(u16 h) {
  union { uint32_t u; float f; } a; a.u = ((uint32_t)h) << 16;
  return a.f;
}

// ---------------- fused weight fp32 -> bf16 (contiguous dst) ----------------
__global__ __launch_bounds__(256) void wconv4(const float* __restrict__ a,
    const float* __restrict__ b, const float* __restrict__ c,
    const float* __restrict__ d, u16* __restrict__ out) {
  int i = blockIdx.x * 256 + threadIdx.x;
  const float* src; int off;
  if (i < 786432)       { src = a; off = i; }
  else if (i < 1048576) { src = b; off = i - 786432; }
  else if (i < 3145728) { src = c; off = i - 1048576; }
  else                  { src = d; off = i - 3145728; }
  out[i] = f2bf(src[off]);
}

// ---------------- LayerNorm (optionally fused shift+window gather) ----------------
template<bool WINDOW>
__global__ __launch_bounds__(256) void ln_win(const float* __restrict__ x,
    const float* __restrict__ gw, const float* __restrict__ bw,
    u16* __restrict__ out) {
  int wid = threadIdx.x >> 6;
  int lane = threadIdx.x & 63;
  int m = (blockIdx.x << 2) + wid;
  const float* src;
  if (WINDOW) {
    int n = m & 63;
    int bwin = m >> 6;
    int b = bwin >> 8;
    int wi = bwin & 255;
    int h = (((wi >> 4) << 3) + (n >> 3) + 4) & 127;
    int w = (((wi & 15) << 3) + (n & 7) + 4) & 127;
    src = x + (((size_t)((b << 7) + h) << 7) + (size_t)w) * 512;
  } else {
    src = x + ((size_t)m << 9);
  }
  int ch = lane << 3;
  float4 v0 = *(const float4*)(src + ch);
  float4 v1 = *(const float4*)(src + ch + 4);
  float vv[8] = {v0.x, v0.y, v0.z, v0.w, v1.x, v1.y, v1.z, v1.w};
  float s = 0.f, s2 = 0.f;
#pragma unroll
  for (int j = 0; j < 8; j++) { s += vv[j]; s2 += vv[j] * vv[j]; }
#pragma unroll
  for (int off = 32; off; off >>= 1) {
    s += __shfl_xor(s, off);
    s2 += __shfl_xor(s2, off);
  }
  float mean = s * (1.f / 512.f);
  float var = s2 * (1.f / 512.f) - mean * mean;
  float rstd = rsqrtf(var + 1e-5f);
  union { uint4 u; u16 h[8]; } pk;
#pragma unroll
  for (int j = 0; j < 8; j++)
    pk.h[j] = f2bf((vv[j] - mean) * rstd * gw[ch + j] + bw[ch + j]);
  *(uint4*)(out + ((size_t)m << 9) + ch) = pk.u;
}

// ---------------- persistent 256-wide-tile 8-phase bf16 MFMA GEMM (B^T weights) ---
// grid = 256 (one block per 256-row m-tile); block loops over T n-tiles with a
// continuous k-tile pipeline (no drain between tiles; epilogue overlapped).
// EPI 0: qkv   -> bf16 out (+bias), ld=1536, T=6
// EPI 1: proj  -> f32 scatter window-reverse+roll + resid + bias -> d_out, T=2
// EPI 2: fc2   -> f32 in-place += into d_out (+bias), ld=512, T=2 (K=2048)
// EPI 3: fc1   -> SwiGLU fused: B-half0 = a rows, B-half1 = gate rows (+2048),
//                 BN=128 output cols, bf16 out, ld=2048, T=16
template<int EPI, int K, int T>
__global__ __launch_bounds__(512, 1) void gemm8(
    const u16* __restrict__ A, const u16* __restrict__ Bw,
    const float* __restrict__ bias, void* __restrict__ outp,
    const float* __restrict__ resid) {
  __shared__ __align__(16) u16 lds[2][4][8192];  // [buf][A0,A1,B0,B1][16KB]
  const int NT = K / 64;
  const int TOT = T * NT;
  int m0 = (int)blockIdx.x << 8;

  int tid = threadIdx.x;
  int wid = tid >> 6, lane = tid & 63;
  int wm = wid >> 2, wn = wid & 3;
  int l15 = lane & 15, lhi = lane >> 4;
  int swz = (lane & 7) << 4;

  int sr0 = tid >> 3;
  int xk = (((tid & 7) ^ ((tid >> 3) & 7)) << 3);  // pre-swizzled source k-offset

  auto stage = [&](int mat, int hh, int gt) {
    if (gt >= TOT) return;
    int tt = gt / NT;
    int ss = gt - tt * NT;
    u16* ld = &lds[gt & 1][mat * 2 + hh][0] + (wid << 9);  // wave-uniform dest
    const u16* g0;
    if (mat == 0) {
      g0 = A + (size_t)(m0 + hh * 128 + sr0) * K + ss * 64 + xk;
    } else {
      int rb;
      if (EPI == 3) rb = (hh ? 2048 : 0) + tt * 128 + sr0;
      else          rb = tt * 256 + hh * 128 + sr0;
      g0 = Bw + (size_t)rb * K + ss * 64 + xk;
    }
    GLD_LDS16(g0, ld);
    GLD_LDS16(g0 + (size_t)64 * K, ld + 4096);
  };

  f32x4 acc[2][4][2][2] = {};   // [qm][i][qn][j]
  bf16x8 afr[4][2], b0r[2][2], b1r[2][2];

  int aoffE = (wm * 64 + l15) * 64;
  int boffE = (wn * 32 + l15) * 64;
  int k0e = ((lhi * 16) ^ swz) >> 1;
  int k1e = ((64 + lhi * 16) ^ swz) >> 1;

  // prologue: per-tile stage order A0,B1,B0,A1 (matches steady state), gt 0 and 1
  stage(0, 0, 0); stage(1, 1, 0); stage(1, 0, 0); stage(0, 1, 0);
  stage(0, 0, 1); stage(1, 1, 1);
  asm volatile("s_waitcnt vmcnt(4)" ::: "memory");
  __builtin_amdgcn_sched_barrier(0);
  __builtin_amdgcn_s_barrier();
  __builtin_amdgcn_sched_barrier(0);

  for (int tt = 0; tt < T; ++tt) {
    for (int ss = 0; ss < NT; ++ss) {
      const int gt = tt * NT + ss;
      const u16* Ah0 = &lds[gt & 1][0][0];
      const u16* Ah1 = &lds[gt & 1][1][0];
      const u16* Bh0 = &lds[gt & 1][2][0];
      const u16* Bh1 = &lds[gt & 1][3][0];

      // ---- phase 0: quadrant (A0,B0); stage B0(gt+1)
#pragma unroll
      for (int i = 0; i < 4; i++) {
        afr[i][0] = *(const bf16x8*)&Ah0[aoffE + i * 1024 + k0e];
        afr[i][1] = *(const bf16x8*)&Ah0[aoffE + i * 1024 + k1e];
      }
#pragma unroll
      for (int j = 0; j < 2; j++) {
        b0r[j][0] = *(const bf16x8*)&Bh0[boffE + j * 1024 + k0e];
        b0r[j][1] = *(const bf16x8*)&Bh0[boffE + j * 1024 + k1e];
      }
      stage(1, 0, gt + 1);
      PB();
      __builtin_amdgcn_s_setprio(1);
#pragma unroll
      for (int i = 0; i < 4; i++)
#pragma unroll
        for (int j = 0; j < 2; j++) {
          ACCUM(acc[0][i][0][j], afr[i][0], b0r[j][0]);
          ACCUM(acc[0][i][0][j], afr[i][1], b0r[j][1]);
        }
      __builtin_amdgcn_s_setprio(0);
      PB();

      // ---- phase 1: quadrant (A0,B1); stage A1(gt+1)
#pragma unroll
      for (int j = 0; j < 2; j++) {
        b1r[j][0] = *(const bf16x8*)&Bh1[boffE + j * 1024 + k0e];
        b1r[j][1] = *(const bf16x8*)&Bh1[boffE + j * 1024 + k1e];
      }
      stage(0, 1, gt + 1);
      PB();
      __builtin_amdgcn_s_setprio(1);
#pragma unroll
      for (int i = 0; i < 4; i++)
#pragma unroll
        for (int j = 0; j < 2; j++) {
          ACCUM(acc[0][i][1][j], afr[i][0], b1r[j][0]);
          ACCUM(acc[0][i][1][j], afr[i][1], b1r[j][1]);
        }
      __builtin_amdgcn_s_setprio(0);
      PB();

      // ---- phase 2: quadrant (A1,B1); stage A0(gt+2)
#pragma unroll
      for (int i = 0; i < 4; i++) {
        afr[i][0] = *(const bf16x8*)&Ah1[aoffE + i * 1024 + k0e];
        afr[i][1] = *(const bf16x8*)&Ah1[aoffE + i * 1024 + k1e];
      }
      stage(0, 0, gt + 2);
      PB();
      __builtin_amdgcn_s_setprio(1);
#pragma unroll
      for (int i = 0; i < 4; i++)
#pragma unroll
        for (int j = 0; j < 2; j++) {
          ACCUM(acc[1][i][1][j], afr[i][0], b1r[j][0]);
          ACCUM(acc[1][i][1][j], afr[i][1], b1r[j][1]);
        }
      __builtin_amdgcn_s_setprio(0);
      PB();

      // ---- phase 3: quadrant (A1,B0) (regs reused); stage B1(gt+2)
      stage(1, 1, gt + 2);
      PB();
      __builtin_amdgcn_s_setprio(1);
#pragma unroll
      for (int i = 0; i < 4; i++)
#pragma unroll
        for (int j = 0; j < 2; j++) {
          ACCUM(acc[1][i][0][j], afr[i][0], b0r[j][0]);
          ACCUM(acc[1][i][0][j], afr[i][1], b0r[j][1]);
        }
      __builtin_amdgcn_s_setprio(0);
      if (gt >= TOT - 2) { asm volatile("s_waitcnt vmcnt(0)" ::: "memory"); }
      else               { asm volatile("s_waitcnt vmcnt(4)" ::: "memory"); }
      __builtin_amdgcn_sched_barrier(0);
      __builtin_amdgcn_s_barrier();
      __builtin_amdgcn_sched_barrier(0);
    }

    // ---------------- epilogue for n-tile tt (overlaps in-flight stages) ------
    {
      int n0 = (EPI == 3) ? (tt << 7) : (tt << 8);
#pragma unroll
      for (int qm = 0; qm < 2; qm++)
#pragma unroll
        for (int i = 0; i < 4; i++) {
          int row = m0 + qm * 128 + wm * 64 + i * 16 + lhi * 4;
          if (EPI == 0) {
            u16* out = (u16*)outp;
#pragma unroll
            for (int qn = 0; qn < 2; qn++)
#pragma unroll
              for (int j = 0; j < 2; j++) {
                int col = n0 + qn * 128 + wn * 32 + j * 16 + l15;
                float bv = bias[col];
#pragma unroll
                for (int rg = 0; rg < 4; rg++)
                  out[(size_t)(row + rg) * 1536 + col] = f2bf(acc[qm][i][qn][j][rg] + bv);
              }
          } else if (EPI == 1) {
            float* out = (float*)outp;
#pragma unroll
            for (int rg = 0; rg < 4; rg++) {
              int m = row + rg;
              int b = m >> 14, wi2 = (m >> 6) & 255, n = m & 63;
              int h = (((wi2 >> 4) << 3) + (n >> 3) + 4) & 127;
              int w = (((wi2 & 15) << 3) + (n & 7) + 4) & 127;
              size_t pix = (((size_t)((b << 7) + h) << 7) + (size_t)w) << 9;
#pragma unroll
              for (int qn = 0; qn < 2; qn++)
#pragma unroll
                for (int j = 0; j < 2; j++) {
                  int col = n0 + qn * 128 + wn * 32 + j * 16 + l15;
                  out[pix + col] = resid[pix + col] + acc[qm][i][qn][j][rg] + bias[col];
                }
            }
          } else if (EPI == 2) {
            float* out = (float*)outp;
#pragma unroll
            for (int qn = 0; qn < 2; qn++)
#pragma unroll
              for (int j = 0; j < 2; j++) {
                int col = n0 + qn * 128 + wn * 32 + j * 16 + l15;
                float bv = bias[col];
#pragma unroll
                for (int rg = 0; rg < 4; rg++) {
                  size_t idx = (size_t)(row + rg) * 512 + col;
                  out[idx] = out[idx] + acc[qm][i][qn][j][rg] + bv;
                }
              }
          } else {
            u16* out = (u16*)outp;
#pragma unroll
            for (int j = 0; j < 2; j++) {
              int col = n0 + wn * 32 + j * 16 + l15;
              float ba_ = bias[col], bg_ = bias[col + 2048];
#pragma unroll
              for (int rg = 0; rg < 4; rg++) {
                float av = acc[qm][i][0][j][rg] + ba_;
                float gv = acc[qm][i][1][j][rg] + bg_;
                float sw = gv / (1.f + __expf(-gv));
                out[(size_t)(row + rg) * 2048 + col] = f2bf(sw * av);
              }
            }
          }
        }
      // zero accumulators for next n-tile
#pragma unroll
      for (int qm = 0; qm < 2; qm++)
#pragma unroll
        for (int i = 0; i < 4; i++)
#pragma unroll
          for (int qn = 0; qn < 2; qn++)
#pragma unroll
            for (int j = 0; j < 2; j++)
              acc[qm][i][qn][j] = (f32x4){0.f, 0.f, 0.f, 0.f};
    }
  }
}

// ---------------- windowed attention, 1 wave per (window, head) ----------------
__global__ __launch_bounds__(64) void attn_kernel(
    const u16* __restrict__ qkv, const float* __restrict__ mask,
    u16* __restrict__ out) {
  __shared__ float Ks[64][33];
  __shared__ float Vs[64][33];
  int bh = blockIdx.x;
  int bwin = bh >> 4;
  int hd = bh & 15;
  int wi = bwin & 255;
  int t = threadIdx.x;
  const u16* base = qkv + (size_t)((bwin << 6) + t) * 1536 + (hd << 5);
  union U { uint4 u; u16 s[8]; };
  float q[32], kv[32];
#pragma unroll
  for (int g = 0; g < 4; g++) {
    U tmp; tmp.u = *(const uint4*)(base + (g << 3));
#pragma unroll
    for (int j = 0; j < 8; j++) q[(g << 3) + j] = bf2f(tmp.s[j]);
  }
#pragma unroll
  for (int g = 0; g < 4; g++) {
    U tmp; tmp.u = *(const uint4*)(base + 512 + (g << 3));
#pragma unroll
    for (int j = 0; j < 8; j++) kv[(g << 3) + j] = bf2f(tmp.s[j]);
  }
  int r = t >> 3, c = t & 7;
#pragma unroll
  for (int d = 0; d < 16; d++) {
    float pos = (d < 8) ? (float)r : (float)c;
    int dd = (d < 8) ? d : (d - 8);
    float ang = pos * __expf(-(float)dd * 1.1512925465f);
    float cs = cosf(ang), sn = sinf(ang);
    float q1 = q[d], q2 = q[d + 16];
    q[d] = q1 * cs - q2 * sn;
    q[d + 16] = q2 * cs + q1 * sn;
    float k1 = kv[d], k2 = kv[d + 16];
    Ks[t][d] = k1 * cs - k2 * sn;
    Ks[t][d + 16] = k2 * cs + k1 * sn;
  }
#pragma unroll
  for (int d = 0; d < 32; d++) q[d] *= 0.17677669529663687f;
#pragma unroll
  for (int g = 0; g < 4; g++) {
    U tmp; tmp.u = *(const uint4*)(base + 1024 + (g << 3));
#pragma unroll
    for (int j = 0; j < 8; j++) Vs[t][(g << 3) + j] = bf2f(tmp.s[j]);
  }
  __syncthreads();
  const float* mrow = mask + (((size_t)wi << 6) + (size_t)t) * 64;
  float p[64];
  float mx = -1e30f;
#pragma unroll
  for (int m = 0; m < 64; m++) {
    float s = 0.f;
#pragma unroll
    for (int d = 0; d < 32; d++) s = fmaf(q[d], Ks[m][d], s);
    s += mrow[m];
    p[m] = s;
    mx = fmaxf(mx, s);
  }
  float sum = 0.f;
#pragma unroll
  for (int m = 0; m < 64; m++) { p[m] = __expf(p[m] - mx); sum += p[m]; }
  float o[32] = {};
#pragma unroll
  for (int m = 0; m < 64; m++)
#pragma unroll
    for (int d = 0; d < 32; d++) o[d] = fmaf(p[m], Vs[m][d], o[d]);
  float inv = 1.f / sum;
  u16* op = out + (size_t)((bwin << 6) + t) * 512 + (hd << 5);
#pragma unroll
  for (int g = 0; g < 4; g++) {
    U tmp;
#pragma unroll
    for (int j = 0; j < 8; j++) tmp.s[j] = f2bf(o[(g << 3) + j] * inv);
    *(uint4*)(op + (g << 3)) = tmp.u;
  }
}

// ---------------- launch ----------------
extern "C" void kernel_launch(void* const* d_in, const int* in_sizes, int n_in,
                              void* d_out, int out_size, void* d_ws, size_t ws_size,
                              hipStream_t stream) {
  (void)in_sizes; (void)n_in; (void)out_size; (void)ws_size;
  const float* x      = (const float*)d_in[0];
  const float* mask   = (const float*)d_in[1];
  const float* n1g    = (const float*)d_in[2];
  const float* n1b    = (const float*)d_in[3];
  const float* qkv_w  = (const float*)d_in[4];
  const float* qkv_b  = (const float*)d_in[5];
  const float* proj_w = (const float*)d_in[6];
  const float* proj_b = (const float*)d_in[7];
  const float* n2g    = (const float*)d_in[8];
  const float* n2b    = (const float*)d_in[9];
  const float* fc1_w  = (const float*)d_in[10];
  const float* fc1_b  = (const float*)d_in[11];
  const float* fc2_w  = (const float*)d_in[12];
  const float* fc2_b  = (const float*)d_in[13];

  char* ws = (char*)d_ws;
  u16* wb_qkv  = (u16*)ws;                  // 1536*512
  u16* wb_proj = wb_qkv + 786432;           // 512*512
  u16* wb_fc1  = wb_proj + 262144;          // 4096*512
  u16* wb_fc2  = wb_fc1 + 2097152;          // 512*2048
  u16* xw      = (u16*)(ws + 8388608);      // xw, later attnout
  u16* qkvb    = (u16*)(ws + 8388608 + 67108864);   // qkv, later y
  u16* yb      = qkvb;
  u16* hb      = (u16*)(ws + 8388608 + 134217728);  // h
  u16* attnout = xw;

  wconv4<<<16384, 256, 0, stream>>>(qkv_w, proj_w, fc1_w, fc2_w, wb_qkv);
  ln_win<true><<<16384, 256, 0, stream>>>(x, n1g, n1b, xw);
  gemm8<0, 512, 6><<<256, 512, 0, stream>>>(xw, wb_qkv, qkv_b, qkvb, nullptr);
  attn_kernel<<<16384, 64, 0, stream>>>(qkvb, mask, attnout);
  gemm8<1, 512, 2><<<256, 512, 0, stream>>>(attnout, wb_proj, proj_b, d_out, x);
  ln_win<false><<<16384, 256, 0, stream>>>((const float*)d_out, n2g, n2b, yb);
  gemm8<3, 512, 16><<<256, 512, 0, stream>>>(yb, wb_fc1, fc1_b, hb, nullptr);
  gemm8<2, 2048, 2><<<256, 512, 0, stream>>>(hb, wb_fc2, fc2_b, d_out, nullptr);
}

// Round 4
// 830.498 us; speedup vs baseline: 2.0102x; 2.0102x over previous
//
#include <hip/hip_runtime.h>
#include <stdint.h>

typedef __attribute__((ext_vector_type(8))) short bf16x8;
typedef __attribute__((ext_vector_type(4))) float f32x4;
typedef unsigned short u16;

#define GLD_LDS16(g, l) __builtin_amdgcn_global_load_lds( \
    (const __attribute__((address_space(1))) void*)(g),   \
    (__attribute__((address_space(3))) void*)(l), 16, 0, 0)

#define PB() do { __builtin_amdgcn_sched_barrier(0); \
                  __builtin_amdgcn_s_barrier();      \
                  __builtin_amdgcn_sched_barrier(0); } while (0)

#define ACCUM(d, a_, b_) d = __builtin_amdgcn_mfma_f32_16x16x32_bf16(a_, b_, d, 0, 0, 0)

__device__ __forceinline__ u16 f2bf(float f) {
  union { float f; uint32_t u; } a; a.f = f;
  uint32_t u = a.u;
  return (u16)((u + 0x7fffu + ((u >> 16) & 1u)) >> 16);
}
__device__ __forceinline__ float bf2f(u16 h) {
  union { uint32_t u; float f; } a; a.u = ((uint32_t)h) << 16;
  return a.f;
}

// ---------------- fused weight fp32 -> bf16 (contiguous dst) ----------------
__global__ __launch_bounds__(256) void wconv4(const float* __restrict__ a,
    const float* __restrict__ b, const float* __restrict__ c,
    const float* __restrict__ d, u16* __restrict__ out) {
  int i = blockIdx.x * 256 + threadIdx.x;
  const float* src; int off;
  if (i < 786432)       { src = a; off = i; }
  else if (i < 1048576) { src = b; off = i - 786432; }
  else if (i < 3145728) { src = c; off = i - 1048576; }
  else                  { src = d; off = i - 3145728; }
  out[i] = f2bf(src[off]);
}

// ---------------- LayerNorm (optionally fused shift+window gather) ----------------
template<bool WINDOW>
__global__ __launch_bounds__(256) void ln_win(const float* __restrict__ x,
    const float* __restrict__ gw, const float* __restrict__ bw,
    u16* __restrict__ out) {
  int wid = threadIdx.x >> 6;
  int lane = threadIdx.x & 63;
  int m = (blockIdx.x << 2) + wid;
  const float* src;
  if (WINDOW) {
    int n = m & 63;
    int bwin = m >> 6;
    int b = bwin >> 8;
    int wi = bwin & 255;
    int h = (((wi >> 4) << 3) + (n >> 3) + 4) & 127;
    int w = (((wi & 15) << 3) + (n & 7) + 4) & 127;
    src = x + (((size_t)((b << 7) + h) << 7) + (size_t)w) * 512;
  } else {
    src = x + ((size_t)m << 9);
  }
  int ch = lane << 3;
  float4 v0 = *(const float4*)(src + ch);
  float4 v1 = *(const float4*)(src + ch + 4);
  float vv[8] = {v0.x, v0.y, v0.z, v0.w, v1.x, v1.y, v1.z, v1.w};
  float s = 0.f, s2 = 0.f;
#pragma unroll
  for (int j = 0; j < 8; j++) { s += vv[j]; s2 += vv[j] * vv[j]; }
#pragma unroll
  for (int off = 32; off; off >>= 1) {
    s += __shfl_xor(s, off);
    s2 += __shfl_xor(s2, off);
  }
  float mean = s * (1.f / 512.f);
  float var = s2 * (1.f / 512.f) - mean * mean;
  float rstd = rsqrtf(var + 1e-5f);
  union { uint4 u; u16 h[8]; } pk;
#pragma unroll
  for (int j = 0; j < 8; j++)
    pk.h[j] = f2bf((vv[j] - mean) * rstd * gw[ch + j] + bw[ch + j]);
  *(uint4*)(out + ((size_t)m << 9) + ch) = pk.u;
}

// ---------------- 256x256-tile 8-phase bf16 MFMA GEMM (B^T weights) ----------------
// (round-2 proven version: tiled grid + bijective XCD swizzle)
template<int EPI, int K>
__global__ __launch_bounds__(512, 1) void gemm8(
    const u16* __restrict__ A, const u16* __restrict__ Bw,
    const float* __restrict__ bias, void* __restrict__ outp,
    const float* __restrict__ resid, int NTN) {
  __shared__ __align__(16) u16 lds[2][4][8192];  // [buf][A0,A1,B0,B1][16KB]
  const int NT = K / 64;
  int bid = blockIdx.x;
  int nwg = gridDim.x;
  int wg = (bid & 7) * (nwg >> 3) + (bid >> 3);   // bijective XCD swizzle (nwg%8==0)
  int mt = wg / NTN, nt = wg - mt * NTN;
  int m0 = mt << 8;
  int n0 = (EPI == 3) ? (nt << 7) : (nt << 8);

  int tid = threadIdx.x;
  int wid = tid >> 6, lane = tid & 63;
  int wm = wid >> 2, wn = wid & 3;
  int l15 = lane & 15, lhi = lane >> 4;
  int swz = (lane & 7) << 4;

  int sr0 = tid >> 3;
  int xk = (((tid & 7) ^ ((tid >> 3) & 7)) << 3);  // pre-swizzled source k-offset

  auto stage = [&](int mat, int hh, int t) {
    if (t >= NT) return;
    u16* ld = &lds[t & 1][mat * 2 + hh][0] + (wid << 9);  // wave-uniform dest
    const u16* g0;
    if (mat == 0) {
      g0 = A + (size_t)(m0 + hh * 128 + sr0) * K + t * 64 + xk;
    } else {
      int rb;
      if (EPI == 3) rb = (hh ? 2048 : 0) + n0 + sr0;
      else          rb = n0 + hh * 128 + sr0;
      g0 = Bw + (size_t)rb * K + t * 64 + xk;
    }
    GLD_LDS16(g0, ld);
    GLD_LDS16(g0 + (size_t)64 * K, ld + 4096);
  };

  f32x4 acc[2][4][2][2] = {};   // [qm][i][qn][j]
  bf16x8 afr[4][2], b0r[2][2], b1r[2][2];

  int aoffE = (wm * 64 + l15) * 64;
  int boffE = (wn * 32 + l15) * 64;
  int k0e = ((lhi * 16) ^ swz) >> 1;
  int k1e = ((64 + lhi * 16) ^ swz) >> 1;

  stage(0, 0, 0); stage(1, 1, 0); stage(1, 0, 0); stage(0, 1, 0);
  stage(0, 0, 1); stage(1, 1, 1);
  asm volatile("s_waitcnt vmcnt(4)" ::: "memory");
  __builtin_amdgcn_sched_barrier(0);
  __builtin_amdgcn_s_barrier();
  __builtin_amdgcn_sched_barrier(0);

  for (int s = 0; s < NT; ++s) {
    const u16* Ah0 = &lds[s & 1][0][0];
    const u16* Ah1 = &lds[s & 1][1][0];
    const u16* Bh0 = &lds[s & 1][2][0];
    const u16* Bh1 = &lds[s & 1][3][0];

    // ---- phase 0: quadrant (A0,B0); stage B0(s+1)
#pragma unroll
    for (int i = 0; i < 4; i++) {
      afr[i][0] = *(const bf16x8*)&Ah0[aoffE + i * 1024 + k0e];
      afr[i][1] = *(const bf16x8*)&Ah0[aoffE + i * 1024 + k1e];
    }
#pragma unroll
    for (int j = 0; j < 2; j++) {
      b0r[j][0] = *(const bf16x8*)&Bh0[boffE + j * 1024 + k0e];
      b0r[j][1] = *(const bf16x8*)&Bh0[boffE + j * 1024 + k1e];
    }
    stage(1, 0, s + 1);
    PB();
    __builtin_amdgcn_s_setprio(1);
#pragma unroll
    for (int i = 0; i < 4; i++)
#pragma unroll
      for (int j = 0; j < 2; j++) {
        ACCUM(acc[0][i][0][j], afr[i][0], b0r[j][0]);
        ACCUM(acc[0][i][0][j], afr[i][1], b0r[j][1]);
      }
    __builtin_amdgcn_s_setprio(0);
    PB();

    // ---- phase 1: quadrant (A0,B1); stage A1(s+1)
#pragma unroll
    for (int j = 0; j < 2; j++) {
      b1r[j][0] = *(const bf16x8*)&Bh1[boffE + j * 1024 + k0e];
      b1r[j][1] = *(const bf16x8*)&Bh1[boffE + j * 1024 + k1e];
    }
    stage(0, 1, s + 1);
    PB();
    __builtin_amdgcn_s_setprio(1);
#pragma unroll
    for (int i = 0; i < 4; i++)
#pragma unroll
      for (int j = 0; j < 2; j++) {
        ACCUM(acc[0][i][1][j], afr[i][0], b1r[j][0]);
        ACCUM(acc[0][i][1][j], afr[i][1], b1r[j][1]);
      }
    __builtin_amdgcn_s_setprio(0);
    PB();

    // ---- phase 2: quadrant (A1,B1); stage A0(s+2)
#pragma unroll
    for (int i = 0; i < 4; i++) {
      afr[i][0] = *(const bf16x8*)&Ah1[aoffE + i * 1024 + k0e];
      afr[i][1] = *(const bf16x8*)&Ah1[aoffE + i * 1024 + k1e];
    }
    stage(0, 0, s + 2);
    PB();
    __builtin_amdgcn_s_setprio(1);
#pragma unroll
    for (int i = 0; i < 4; i++)
#pragma unroll
      for (int j = 0; j < 2; j++) {
        ACCUM(acc[1][i][1][j], afr[i][0], b1r[j][0]);
        ACCUM(acc[1][i][1][j], afr[i][1], b1r[j][1]);
      }
    __builtin_amdgcn_s_setprio(0);
    PB();

    // ---- phase 3: quadrant (A1,B0) (regs reused); stage B1(s+2)
    stage(1, 1, s + 2);
    PB();
    __builtin_amdgcn_s_setprio(1);
#pragma unroll
    for (int i = 0; i < 4; i++)
#pragma unroll
      for (int j = 0; j < 2; j++) {
        ACCUM(acc[1][i][0][j], afr[i][0], b0r[j][0]);
        ACCUM(acc[1][i][0][j], afr[i][1], b0r[j][1]);
      }
    __builtin_amdgcn_s_setprio(0);
    if (s >= NT - 2) { asm volatile("s_waitcnt vmcnt(0)" ::: "memory"); }
    else             { asm volatile("s_waitcnt vmcnt(4)" ::: "memory"); }
    __builtin_amdgcn_sched_barrier(0);
    __builtin_amdgcn_s_barrier();
    __builtin_amdgcn_sched_barrier(0);
  }

  // ---------------- epilogue ----------------
#pragma unroll
  for (int qm = 0; qm < 2; qm++)
#pragma unroll
    for (int i = 0; i < 4; i++) {
      int row = m0 + qm * 128 + wm * 64 + i * 16 + lhi * 4;
      if (EPI == 0) {
        u16* out = (u16*)outp;
#pragma unroll
        for (int qn = 0; qn < 2; qn++)
#pragma unroll
          for (int j = 0; j < 2; j++) {
            int col = n0 + qn * 128 + wn * 32 + j * 16 + l15;
            float bv = bias[col];
#pragma unroll
            for (int rg = 0; rg < 4; rg++)
              out[(size_t)(row + rg) * 1536 + col] = f2bf(acc[qm][i][qn][j][rg] + bv);
          }
      } else if (EPI == 1) {
        float* out = (float*)outp;
#pragma unroll
        for (int rg = 0; rg < 4; rg++) {
          int m = row + rg;
          int b = m >> 14, wi2 = (m >> 6) & 255, n = m & 63;
          int h = (((wi2 >> 4) << 3) + (n >> 3) + 4) & 127;
          int w = (((wi2 & 15) << 3) + (n & 7) + 4) & 127;
          size_t pix = (((size_t)((b << 7) + h) << 7) + (size_t)w) << 9;
#pragma unroll
          for (int qn = 0; qn < 2; qn++)
#pragma unroll
            for (int j = 0; j < 2; j++) {
              int col = n0 + qn * 128 + wn * 32 + j * 16 + l15;
              out[pix + col] = resid[pix + col] + acc[qm][i][qn][j][rg] + bias[col];
            }
        }
      } else if (EPI == 2) {
        float* out = (float*)outp;
#pragma unroll
        for (int qn = 0; qn < 2; qn++)
#pragma unroll
          for (int j = 0; j < 2; j++) {
            int col = n0 + qn * 128 + wn * 32 + j * 16 + l15;
            float bv = bias[col];
#pragma unroll
            for (int rg = 0; rg < 4; rg++) {
              size_t idx = (size_t)(row + rg) * 512 + col;
              out[idx] = out[idx] + acc[qm][i][qn][j][rg] + bv;
            }
          }
      } else {
        u16* out = (u16*)outp;
#pragma unroll
        for (int j = 0; j < 2; j++) {
          int col = n0 + wn * 32 + j * 16 + l15;
          float ba_ = bias[col], bg_ = bias[col + 2048];
#pragma unroll
          for (int rg = 0; rg < 4; rg++) {
            float av = acc[qm][i][0][j][rg] + ba_;
            float gv = acc[qm][i][1][j][rg] + bg_;
            float sw = gv / (1.f + __expf(-gv));
            out[(size_t)(row + rg) * 2048 + col] = f2bf(sw * av);
          }
        }
      }
    }
}

// ---------------- MFMA windowed attention: 1 wave per (window, head) -------------
// S^T = mfma(K, Q); in-register softmax over S^T columns; P^T -> LDS (cvt_pk b64);
// O^T = mfma(V^T, P^T). All LDS wave-private: no barriers. Mask computed (wr/wc==15).
__global__ __launch_bounds__(256) void attn_mfma(
    const u16* __restrict__ qkv, u16* __restrict__ out) {
  __shared__ __align__(16) char alds[4][15360];
  int tid = threadIdx.x;
  int wid = tid >> 6, lane = tid & 63;
  int bwin = blockIdx.x >> 2;
  int head = ((blockIdx.x & 3) << 2) + wid;
  int wi = bwin & 255;
  int wr = wi >> 4, wc = wi & 15;
  char* Wb = alds[wid];
  u16* Qr = (u16*)Wb;                 // [64] rows, 40 u16 stride (80B)
  u16* Kr = (u16*)(Wb + 5120);
  u16* Vt = (u16*)(Wb + 10240);       // [32][72 u16] (144B stride)
  u16* PT = (u16*)Wb;                 // [64][72 u16] — overlaps Qr/Kr after S
  int t = lane;
  int l15 = lane & 15, lhi = lane >> 4;
  const u16* base = qkv + (size_t)((bwin << 6) + t) * 1536 + (head << 5);
  union U { uint4 u; u16 s[8]; };
  U vq[4], vk[4], vv[4];
#pragma unroll
  for (int g = 0; g < 4; g++) {
    vq[g].u = *(const uint4*)(base + (g << 3));
    vk[g].u = *(const uint4*)(base + 512 + (g << 3));
    vv[g].u = *(const uint4*)(base + 1024 + (g << 3));
  }
  float q[32], k[32];
#pragma unroll
  for (int j = 0; j < 32; j++) {
    q[j] = bf2f(vq[j >> 3].s[j & 7]);
    k[j] = bf2f(vk[j >> 3].s[j & 7]);
  }
  int r = t >> 3, c = t & 7;
#pragma unroll
  for (int d = 0; d < 16; d++) {
    float pos = (d < 8) ? (float)r : (float)c;
    int dd = (d < 8) ? d : d - 8;
    float ang = pos * __expf(-(float)dd * 1.1512925465f);  // 10000^(-dd/8)
    float sn, cs;
    __sincosf(ang, &sn, &cs);
    float q1 = q[d], q2 = q[d + 16];
    q[d] = q1 * cs - q2 * sn;  q[d + 16] = q2 * cs + q1 * sn;
    float k1 = k[d], k2 = k[d + 16];
    k[d] = k1 * cs - k2 * sn;  k[d + 16] = k2 * cs + k1 * sn;
  }
#pragma unroll
  for (int j = 0; j < 32; j++) q[j] *= 0.17677669529663687f;  // 32^-0.5
  // stage Q, K row-major (padded stride) and V transposed
#pragma unroll
  for (int sl = 0; sl < 4; sl++) {
    U tq, tk;
#pragma unroll
    for (int j = 0; j < 8; j++) { tq.s[j] = f2bf(q[sl * 8 + j]); tk.s[j] = f2bf(k[sl * 8 + j]); }
    *(uint4*)(Qr + t * 40 + sl * 8) = tq.u;
    *(uint4*)(Kr + t * 40 + sl * 8) = tk.u;
  }
#pragma unroll
  for (int j = 0; j < 32; j++) Vt[j * 72 + t] = vv[j >> 3].s[j & 7];
  // ---- S^T = K · Q^T : 16 mfma; C layout: row=m (lhi*4+reg), col=q (l15)
  bf16x8 kf[4], qf[4];
#pragma unroll
  for (int i = 0; i < 4; i++) {
    kf[i] = *(const bf16x8*)(Kr + (i * 16 + l15) * 40 + lhi * 8);
    qf[i] = *(const bf16x8*)(Qr + (i * 16 + l15) * 40 + lhi * 8);
  }
  f32x4 zz = {0.f, 0.f, 0.f, 0.f};
  f32x4 st[4][4];
#pragma unroll
  for (int mi = 0; mi < 4; mi++)
#pragma unroll
    for (int nj = 0; nj < 4; nj++)
      st[mi][nj] = __builtin_amdgcn_mfma_f32_16x16x32_bf16(kf[mi], qf[nj], zz, 0, 0, 0);
  // ---- computed swin mask (only boundary windows wr==15 / wc==15 are nonzero)
  if (wr == 15 || wc == 15) {
    int idh = (wr == 15) ? ((r >= 4) ? 2 : 1) : 0;
    int idw = (wc == 15) ? ((c >= 4) ? 2 : 1) : 0;
    int code = idh * 3 + idw;
    int cq[4], cm[4][4];
#pragma unroll
    for (int nj = 0; nj < 4; nj++) cq[nj] = __shfl(code, nj * 16 + l15);
#pragma unroll
    for (int mi = 0; mi < 4; mi++)
#pragma unroll
      for (int rg = 0; rg < 4; rg++) cm[mi][rg] = __shfl(code, mi * 16 + lhi * 4 + rg);
#pragma unroll
    for (int mi = 0; mi < 4; mi++)
#pragma unroll
      for (int nj = 0; nj < 4; nj++)
#pragma unroll
        for (int rg = 0; rg < 4; rg++)
          if (cm[mi][rg] != cq[nj]) st[mi][nj][rg] -= 100.f;
  }
  // ---- softmax over columns q: reduce rows (16 in-lane x 4 lhi lanes)
  float inv_[4];
#pragma unroll
  for (int nj = 0; nj < 4; nj++) {
    float mx = -1e30f;
#pragma unroll
    for (int mi = 0; mi < 4; mi++)
#pragma unroll
      for (int rg = 0; rg < 4; rg++) mx = fmaxf(mx, st[mi][nj][rg]);
    mx = fmaxf(mx, __shfl_xor(mx, 16));
    mx = fmaxf(mx, __shfl_xor(mx, 32));
    float sum = 0.f;
#pragma unroll
    for (int mi = 0; mi < 4; mi++)
#pragma unroll
      for (int rg = 0; rg < 4; rg++) {
        float p = __expf(st[mi][nj][rg] - mx);
        st[mi][nj][rg] = p;
        sum += p;
      }
    sum += __shfl_xor(sum, 16);
    sum += __shfl_xor(sum, 32);
    inv_[nj] = 1.f / sum;
  }
  // ---- P^T -> LDS [q][m] (m-contiguous: 4 C-regs pack into one b64 write)
#pragma unroll
  for (int mi = 0; mi < 4; mi++)
#pragma unroll
    for (int nj = 0; nj < 4; nj++) {
      uint32_t lo, hi;
      asm("v_cvt_pk_bf16_f32 %0, %1, %2" : "=v"(lo) : "v"(st[mi][nj][0]), "v"(st[mi][nj][1]));
      asm("v_cvt_pk_bf16_f32 %0, %1, %2" : "=v"(hi) : "v"(st[mi][nj][2]), "v"(st[mi][nj][3]));
      uint2 pr; pr.x = lo; pr.y = hi;
      *(uint2*)(PT + (nj * 16 + l15) * 72 + mi * 16 + lhi * 4) = pr;
    }
  // ---- O^T = V^T · P^T : 16 mfma; write out (row=d, col=q)
  bf16x8 vf[2][2], pf[4][2];
#pragma unroll
  for (int i = 0; i < 2; i++)
#pragma unroll
    for (int kc = 0; kc < 2; kc++)
      vf[i][kc] = *(const bf16x8*)(Vt + (i * 16 + l15) * 72 + kc * 32 + lhi * 8);
#pragma unroll
  for (int nj = 0; nj < 4; nj++)
#pragma unroll
    for (int kc = 0; kc < 2; kc++)
      pf[nj][kc] = *(const bf16x8*)(PT + (nj * 16 + l15) * 72 + kc * 32 + lhi * 8);
#pragma unroll
  for (int i = 0; i < 2; i++)
#pragma unroll
    for (int nj = 0; nj < 4; nj++) {
      f32x4 o = __builtin_amdgcn_mfma_f32_16x16x32_bf16(vf[i][0], pf[nj][0], zz, 0, 0, 0);
      o = __builtin_amdgcn_mfma_f32_16x16x32_bf16(vf[i][1], pf[nj][1], o, 0, 0, 0);
      float iv = inv_[nj];
      float o0 = o[0] * iv, o1 = o[1] * iv, o2 = o[2] * iv, o3 = o[3] * iv;
      uint32_t lo, hi;
      asm("v_cvt_pk_bf16_f32 %0, %1, %2" : "=v"(lo) : "v"(o0), "v"(o1));
      asm("v_cvt_pk_bf16_f32 %0, %1, %2" : "=v"(hi) : "v"(o2), "v"(o3));
      uint2 pr; pr.x = lo; pr.y = hi;
      *(uint2*)(out + (size_t)((bwin << 6) + nj * 16 + l15) * 512 + (head << 5) + i * 16 + lhi * 4) = pr;
    }
}

// ---------------- launch ----------------
extern "C" void kernel_launch(void* const* d_in, const int* in_sizes, int n_in,
                              void* d_out, int out_size, void* d_ws, size_t ws_size,
                              hipStream_t stream) {
  (void)in_sizes; (void)n_in; (void)out_size; (void)ws_size;
  const float* x      = (const float*)d_in[0];
  const float* n1g    = (const float*)d_in[2];
  const float* n1b    = (const float*)d_in[3];
  const float* qkv_w  = (const float*)d_in[4];
  const float* qkv_b  = (const float*)d_in[5];
  const float* proj_w = (const float*)d_in[6];
  const float* proj_b = (const float*)d_in[7];
  const float* n2g    = (const float*)d_in[8];
  const float* n2b    = (const float*)d_in[9];
  const float* fc1_w  = (const float*)d_in[10];
  const float* fc1_b  = (const float*)d_in[11];
  const float* fc2_w  = (const float*)d_in[12];
  const float* fc2_b  = (const float*)d_in[13];

  char* ws = (char*)d_ws;
  u16* wb_qkv  = (u16*)ws;                  // 1536*512
  u16* wb_proj = wb_qkv + 786432;           // 512*512
  u16* wb_fc1  = wb_proj + 262144;          // 4096*512
  u16* wb_fc2  = wb_fc1 + 2097152;          // 512*2048
  u16* xw      = (u16*)(ws + 8388608);      // xw, later attnout
  u16* qkvb    = (u16*)(ws + 8388608 + 67108864);   // qkv, later y
  u16* yb      = qkvb;
  u16* hb      = (u16*)(ws + 8388608 + 134217728);  // h
  u16* attnout = xw;

  wconv4<<<16384, 256, 0, stream>>>(qkv_w, proj_w, fc1_w, fc2_w, wb_qkv);
  ln_win<true><<<16384, 256, 0, stream>>>(x, n1g, n1b, xw);
  gemm8<0, 512><<<1536, 512, 0, stream>>>(xw, wb_qkv, qkv_b, qkvb, nullptr, 6);
  attn_mfma<<<4096, 256, 0, stream>>>(qkvb, attnout);
  gemm8<1, 512><<<512, 512, 0, stream>>>(attnout, wb_proj, proj_b, d_out, x, 2);
  ln_win<false><<<16384, 256, 0, stream>>>((const float*)d_out, n2g, n2b, yb);
  gemm8<3, 512><<<4096, 512, 0, stream>>>(yb, wb_fc1, fc1_b, hb, nullptr, 16);
  gemm8<2, 2048><<<512, 512, 0, stream>>>(hb, wb_fc2, fc2_b, d_out, nullptr, 2);
}